// Round 1
// baseline (754.238 us; speedup 1.0000x reference)
//
#include <hip/hip_runtime.h>

#define N_NODE 100000
#define N_EDGE 800000
#define IN_DIM 128
#define OUT_DIM 128
#define ATTN 64
#define N_RELA 401
#define BATCH 64
#define ENC_NEG_INF 0x007FFFFFu

// Order-preserving float->uint encoding: unsigned compare == float compare.
__device__ __forceinline__ unsigned encf(float f) {
    unsigned b = __float_as_uint(f);
    return (b & 0x80000000u) ? ~b : (b | 0x80000000u);
}
__device__ __forceinline__ float decf(unsigned u) {
    unsigned b = (u & 0x80000000u) ? (u & 0x7FFFFFFFu) : ~u;
    return __uint_as_float(b);
}

// ---------------- sW[node][a] = dot(hidden[node,:], Ws[:,a]) ----------------
// 64 threads (one wave) per block, 8 nodes per block, float4 k-unroll.
__global__ __launch_bounds__(64) void k_sw(const float* __restrict__ hidden,
                                           const float* __restrict__ Ws,
                                           float* __restrict__ sW) {
    __shared__ float h[8][IN_DIM];
    const int t = threadIdx.x;
    const long base = (long)blockIdx.x * 8;
    const float4* hp = (const float4*)(hidden + base * IN_DIM);
    float4* hl = (float4*)(&h[0][0]);
#pragma unroll
    for (int i = 0; i < 4; ++i) hl[i * 64 + t] = hp[i * 64 + t];
    __syncthreads();
    float acc[8] = {0.f, 0.f, 0.f, 0.f, 0.f, 0.f, 0.f, 0.f};
    for (int kq = 0; kq < IN_DIM / 4; ++kq) {
        const float w0 = Ws[(4 * kq + 0) * ATTN + t];
        const float w1 = Ws[(4 * kq + 1) * ATTN + t];
        const float w2 = Ws[(4 * kq + 2) * ATTN + t];
        const float w3 = Ws[(4 * kq + 3) * ATTN + t];
#pragma unroll
        for (int j = 0; j < 8; ++j) {
            float4 av = *(const float4*)(&h[j][4 * kq]);
            acc[j] = fmaf(av.x, w0, acc[j]);
            acc[j] = fmaf(av.y, w1, acc[j]);
            acc[j] = fmaf(av.z, w2, acc[j]);
            acc[j] = fmaf(av.w, w3, acc[j]);
        }
    }
#pragma unroll
    for (int j = 0; j < 8; ++j) sW[(base + j) * ATTN + t] = acc[j];
}

// ------- rW[r][a] = rela[r] @ Wr ;  qW[b][a] = rela[q_rel[b]] @ Wqr + bqr ----
__global__ __launch_bounds__(64) void k_relq(const float* __restrict__ rela,
                                             const float* __restrict__ Wr,
                                             const float* __restrict__ Wqr,
                                             const float* __restrict__ bqr,
                                             const int* __restrict__ q_rel,
                                             float* __restrict__ rW,
                                             float* __restrict__ qW) {
    const int t = threadIdx.x;
    const int b = blockIdx.x;
    if (b < N_RELA) {
        const float* h = rela + (long)b * IN_DIM;
        float acc = 0.f;
        for (int k = 0; k < IN_DIM; ++k) acc = fmaf(h[k], Wr[k * ATTN + t], acc);
        rW[b * ATTN + t] = acc;
    } else {
        const int q = b - N_RELA;
        const float* h = rela + (long)q_rel[q] * IN_DIM;
        float acc = bqr[t];
        for (int k = 0; k < IN_DIM; ++k) acc = fmaf(h[k], Wqr[k * ATTN + t], acc);
        qW[q * ATTN + t] = acc;
    }
}

// ---------------- agg init to encoded(-inf) ----------------
__global__ __launch_bounds__(256) void k_init(unsigned* __restrict__ agg) {
    const int i = blockIdx.x * 256 + threadIdx.x;
    agg[i] = ENC_NEG_INF;  // grid sized exactly to N_NODE*IN_DIM
}

// ---------------- per-edge: attn -> alpha -> message -> atomicMax ----------
// One wave (64 lanes) per edge; 4 edges per 256-thread block.
__global__ __launch_bounds__(256) void k_edge(const int* __restrict__ edges,
                                              const float* __restrict__ hidden,
                                              const float* __restrict__ rela,
                                              const float* __restrict__ sW,
                                              const float* __restrict__ rW,
                                              const float* __restrict__ qW,
                                              const float* __restrict__ wa,
                                              const float* __restrict__ ba,
                                              unsigned* __restrict__ agg) {
    const int wave = threadIdx.x >> 6;
    const int lane = threadIdx.x & 63;
    const long e = (long)blockIdx.x * 4 + wave;
    if (e >= N_EDGE) return;
    const int* ed = edges + e * 6;
    const int2 p0 = *(const int2*)(ed);      // [r_idx, 0]
    const int2 p1 = *(const int2*)(ed + 2);  // [rel,   0]
    const int2 p2 = *(const int2*)(ed + 4);  // [sub, obj]
    const int r_idx = p0.x, rel = p1.x, sub = p2.x, obj = p2.y;

    float attn = sW[(long)sub * ATTN + lane] + rW[rel * ATTN + lane] +
                 qW[r_idx * ATTN + lane];
    attn = fmaxf(attn, 0.f);
    float p = attn * wa[lane];
    p += __shfl_xor(p, 32);
    p += __shfl_xor(p, 16);
    p += __shfl_xor(p, 8);
    p += __shfl_xor(p, 4);
    p += __shfl_xor(p, 2);
    p += __shfl_xor(p, 1);
    const float alpha = 1.f / (1.f + __expf(-(p + ba[0])));

    const float2 hs = ((const float2*)(hidden + (long)sub * IN_DIM))[lane];
    const float2 hr = ((const float2*)(rela + (long)rel * IN_DIM))[lane];
    const float m0 = alpha * (hs.x + hr.x);
    const float m1 = alpha * (hs.y + hr.y);
    unsigned* dst = agg + (long)obj * IN_DIM + 2 * lane;
    atomicMax(dst, encf(m0));
    atomicMax(dst + 1, encf(m1));
}

// ---------------- out = decode(agg) @ W_h ----------------
// 64 threads per block, 8 nodes per block, each thread owns cols t and t+64.
__global__ __launch_bounds__(64) void k_out(const unsigned* __restrict__ agg,
                                            const float* __restrict__ W_h,
                                            float* __restrict__ out) {
    __shared__ float a[8][IN_DIM];
    const int t = threadIdx.x;
    const long base = (long)blockIdx.x * 8;
#pragma unroll
    for (int j = 0; j < 8; ++j) {
        const unsigned u0 = agg[(base + j) * IN_DIM + t];
        const unsigned u1 = agg[(base + j) * IN_DIM + t + 64];
        a[j][t] = (u0 == ENC_NEG_INF) ? 0.f : decf(u0);
        a[j][t + 64] = (u1 == ENC_NEG_INF) ? 0.f : decf(u1);
    }
    __syncthreads();
    float acc0[8] = {0.f, 0.f, 0.f, 0.f, 0.f, 0.f, 0.f, 0.f};
    float acc1[8] = {0.f, 0.f, 0.f, 0.f, 0.f, 0.f, 0.f, 0.f};
    for (int kq = 0; kq < IN_DIM / 4; ++kq) {
        const float w00 = W_h[(4 * kq + 0) * OUT_DIM + t];
        const float w10 = W_h[(4 * kq + 1) * OUT_DIM + t];
        const float w20 = W_h[(4 * kq + 2) * OUT_DIM + t];
        const float w30 = W_h[(4 * kq + 3) * OUT_DIM + t];
        const float w01 = W_h[(4 * kq + 0) * OUT_DIM + t + 64];
        const float w11 = W_h[(4 * kq + 1) * OUT_DIM + t + 64];
        const float w21 = W_h[(4 * kq + 2) * OUT_DIM + t + 64];
        const float w31 = W_h[(4 * kq + 3) * OUT_DIM + t + 64];
#pragma unroll
        for (int j = 0; j < 8; ++j) {
            float4 av = *(const float4*)(&a[j][4 * kq]);
            acc0[j] = fmaf(av.x, w00, acc0[j]);
            acc0[j] = fmaf(av.y, w10, acc0[j]);
            acc0[j] = fmaf(av.z, w20, acc0[j]);
            acc0[j] = fmaf(av.w, w30, acc0[j]);
            acc1[j] = fmaf(av.x, w01, acc1[j]);
            acc1[j] = fmaf(av.y, w11, acc1[j]);
            acc1[j] = fmaf(av.z, w21, acc1[j]);
            acc1[j] = fmaf(av.w, w31, acc1[j]);
        }
    }
#pragma unroll
    for (int j = 0; j < 8; ++j) {
        out[(base + j) * OUT_DIM + t] = acc0[j];
        out[(base + j) * OUT_DIM + t + 64] = acc1[j];
    }
}

extern "C" void kernel_launch(void* const* d_in, const int* in_sizes, int n_in,
                              void* d_out, int out_size, void* d_ws, size_t ws_size,
                              hipStream_t stream) {
    const int* q_rel = (const int*)d_in[1];
    const float* hidden = (const float*)d_in[2];
    const int* edges = (const int*)d_in[3];
    const float* rela = (const float*)d_in[7];
    const float* Ws = (const float*)d_in[8];
    const float* Wr = (const float*)d_in[9];
    const float* Wqr = (const float*)d_in[10];
    const float* bqr = (const float*)d_in[11];
    const float* wa = (const float*)d_in[12];
    const float* ba = (const float*)d_in[13];
    const float* W_h = (const float*)d_in[14];
    float* out = (float*)d_out;

    char* ws = (char*)d_ws;
    float* sW = (float*)(ws);                    // 100000*64*4  = 25,600,000 B
    float* rW = (float*)(ws + 25600000);         // 401*64*4     =    102,656 B
    float* qW = (float*)(ws + 25702656);         // 64*64*4      =     16,384 B
    unsigned* agg = (unsigned*)(ws + 25719040);  // 100000*128*4 = 51,200,000 B

    hipLaunchKernelGGL(k_init, dim3((N_NODE * IN_DIM) / 256), dim3(256), 0, stream, agg);
    hipLaunchKernelGGL(k_sw, dim3(N_NODE / 8), dim3(64), 0, stream, hidden, Ws, sW);
    hipLaunchKernelGGL(k_relq, dim3(N_RELA + BATCH), dim3(64), 0, stream,
                       rela, Wr, Wqr, bqr, q_rel, rW, qW);
    hipLaunchKernelGGL(k_edge, dim3(N_EDGE / 4), dim3(256), 0, stream,
                       edges, hidden, rela, sW, rW, qW, wa, ba, agg);
    hipLaunchKernelGGL(k_out, dim3(N_NODE / 8), dim3(64), 0, stream, agg, W_h, out);
}

// Round 2
// 507.417 us; speedup vs baseline: 1.4864x; 1.4864x over previous
//
#include <hip/hip_runtime.h>

#define N_NODE 100000
#define N_EDGE 800000
#define IN_DIM 128
#define OUT_DIM 128
#define ATTN 64
#define N_RELA 401
#define BATCH 64

#define SCAN_B 256
#define N_SCANB ((N_NODE + SCAN_B - 1) / SCAN_B)  // 391

// ---------------- sW[node][a] = dot(hidden[node,:], Ws[:,a]) ----------------
__global__ __launch_bounds__(64) void k_sw(const float* __restrict__ hidden,
                                           const float* __restrict__ Ws,
                                           float* __restrict__ sW) {
    __shared__ float h[8][IN_DIM];
    const int t = threadIdx.x;
    const long base = (long)blockIdx.x * 8;
    const float4* hp = (const float4*)(hidden + base * IN_DIM);
    float4* hl = (float4*)(&h[0][0]);
#pragma unroll
    for (int i = 0; i < 4; ++i) hl[i * 64 + t] = hp[i * 64 + t];
    __syncthreads();
    float acc[8] = {0.f, 0.f, 0.f, 0.f, 0.f, 0.f, 0.f, 0.f};
    for (int kq = 0; kq < IN_DIM / 4; ++kq) {
        const float w0 = Ws[(4 * kq + 0) * ATTN + t];
        const float w1 = Ws[(4 * kq + 1) * ATTN + t];
        const float w2 = Ws[(4 * kq + 2) * ATTN + t];
        const float w3 = Ws[(4 * kq + 3) * ATTN + t];
#pragma unroll
        for (int j = 0; j < 8; ++j) {
            float4 av = *(const float4*)(&h[j][4 * kq]);
            acc[j] = fmaf(av.x, w0, acc[j]);
            acc[j] = fmaf(av.y, w1, acc[j]);
            acc[j] = fmaf(av.z, w2, acc[j]);
            acc[j] = fmaf(av.w, w3, acc[j]);
        }
    }
#pragma unroll
    for (int j = 0; j < 8; ++j) sW[(base + j) * ATTN + t] = acc[j];
}

// ------- rW[r][a] = rela[r] @ Wr ;  qW[b][a] = rela[q_rel[b]] @ Wqr + bqr ----
__global__ __launch_bounds__(64) void k_relq(const float* __restrict__ rela,
                                             const float* __restrict__ Wr,
                                             const float* __restrict__ Wqr,
                                             const float* __restrict__ bqr,
                                             const int* __restrict__ q_rel,
                                             float* __restrict__ rW,
                                             float* __restrict__ qW) {
    const int t = threadIdx.x;
    const int b = blockIdx.x;
    if (b < N_RELA) {
        const float* h = rela + (long)b * IN_DIM;
        float acc = 0.f;
        for (int k = 0; k < IN_DIM; ++k) acc = fmaf(h[k], Wr[k * ATTN + t], acc);
        rW[b * ATTN + t] = acc;
    } else {
        const int q = b - N_RELA;
        const float* h = rela + (long)q_rel[q] * IN_DIM;
        float acc = bqr[t];
        for (int k = 0; k < IN_DIM; ++k) acc = fmaf(h[k], Wqr[k * ATTN + t], acc);
        qW[q * ATTN + t] = acc;
    }
}

// ---------------- counting sort of edges by obj ----------------
__global__ __launch_bounds__(256) void k_zero(int* __restrict__ cnt) {
    const int i = blockIdx.x * 256 + threadIdx.x;
    if (i < N_NODE) cnt[i] = 0;
}

__global__ __launch_bounds__(256) void k_count(const int* __restrict__ edges,
                                               int* __restrict__ cnt) {
    const int e = blockIdx.x * 256 + threadIdx.x;
    if (e < N_EDGE) atomicAdd(&cnt[edges[e * 6 + 5]], 1);
}

// per-block inclusive scan (Hillis-Steele) + block sums
__global__ __launch_bounds__(SCAN_B) void k_scan1(const int* __restrict__ cnt,
                                                  int* __restrict__ incl,
                                                  int* __restrict__ bsum) {
    __shared__ int s[SCAN_B];
    const int i = blockIdx.x * SCAN_B + threadIdx.x;
    s[threadIdx.x] = (i < N_NODE) ? cnt[i] : 0;
    __syncthreads();
    for (int off = 1; off < SCAN_B; off <<= 1) {
        int v = (threadIdx.x >= off) ? s[threadIdx.x - off] : 0;
        __syncthreads();
        s[threadIdx.x] += v;
        __syncthreads();
    }
    if (i < N_NODE) incl[i] = s[threadIdx.x];
    if (threadIdx.x == SCAN_B - 1) bsum[blockIdx.x] = s[SCAN_B - 1];
}

// single-block scan of the 391 block sums
__global__ __launch_bounds__(512) void k_scan2(int* __restrict__ bsum) {
    __shared__ int s[512];
    const int t = threadIdx.x;
    s[t] = (t < N_SCANB) ? bsum[t] : 0;
    __syncthreads();
    for (int off = 1; off < 512; off <<= 1) {
        int v = (t >= off) ? s[t - off] : 0;
        __syncthreads();
        s[t] += v;
        __syncthreads();
    }
    if (t < N_SCANB) bsum[t] = s[t];
}

__global__ __launch_bounds__(SCAN_B) void k_scan3(const int* __restrict__ incl,
                                                  const int* __restrict__ cnt,
                                                  const int* __restrict__ bsum,
                                                  int* __restrict__ offs,
                                                  int* __restrict__ cursor) {
    const int i = blockIdx.x * SCAN_B + threadIdx.x;
    if (i >= N_NODE) return;
    const int base = blockIdx.x ? bsum[blockIdx.x - 1] : 0;
    const int off = base + incl[i] - cnt[i];  // exclusive prefix
    offs[i] = off;
    cursor[i] = off;
}

// scatter packed record: sub(17b) << 15 | rel(9b) << 6 | r_idx(6b)
__global__ __launch_bounds__(256) void k_scatter(const int* __restrict__ edges,
                                                 int* __restrict__ cursor,
                                                 unsigned* __restrict__ rec) {
    const int e = blockIdx.x * 256 + threadIdx.x;
    if (e >= N_EDGE) return;
    const int* ed = edges + (long)e * 6;
    const int2 p0 = *(const int2*)(ed);      // [r_idx, 0]
    const int2 p1 = *(const int2*)(ed + 2);  // [rel,   0]
    const int2 p2 = *(const int2*)(ed + 4);  // [sub, obj]
    const int pos = atomicAdd(&cursor[p2.y], 1);
    rec[pos] = ((unsigned)p2.x << 15) | ((unsigned)p1.x << 6) | (unsigned)p0.x;
}

// ---- fused: per-node gather-max (wave per node) + @W_h epilogue (8 nodes/blk)
__global__ __launch_bounds__(512) void k_fused(const unsigned* __restrict__ rec,
                                               const int* __restrict__ offs,
                                               const int* __restrict__ cnt,
                                               const float* __restrict__ hidden,
                                               const float* __restrict__ rela,
                                               const float* __restrict__ sW,
                                               const float* __restrict__ rW,
                                               const float* __restrict__ qW,
                                               const float* __restrict__ wa,
                                               const float* __restrict__ ba,
                                               const float* __restrict__ W_h,
                                               float* __restrict__ out) {
    __shared__ float a[8][IN_DIM];
    const int wv = threadIdx.x >> 6;    // wave in block = node in group of 8
    const int lane = threadIdx.x & 63;
    const long node = (long)blockIdx.x * 8 + wv;  // N_NODE % 8 == 0
    const int start = offs[node];
    const int deg = cnt[node];
    const float wal = wa[lane];
    const float bav = ba[0];
    float m0 = -INFINITY, m1 = -INFINITY;
    for (int i = 0; i < deg; ++i) {
        const unsigned r = rec[start + i];
        const int r_idx = r & 63;
        const int rel = (r >> 6) & 511;
        const int sub = (int)(r >> 15);
        float attn = sW[(long)sub * ATTN + lane] + rW[rel * ATTN + lane] +
                     qW[r_idx * ATTN + lane];
        attn = fmaxf(attn, 0.f);
        float p = attn * wal;
        p += __shfl_xor(p, 32);
        p += __shfl_xor(p, 16);
        p += __shfl_xor(p, 8);
        p += __shfl_xor(p, 4);
        p += __shfl_xor(p, 2);
        p += __shfl_xor(p, 1);
        const float alpha = 1.f / (1.f + __expf(-(p + bav)));
        const float2 hs = ((const float2*)(hidden + (long)sub * IN_DIM))[lane];
        const float2 hr = ((const float2*)(rela + (long)rel * IN_DIM))[lane];
        m0 = fmaxf(m0, alpha * (hs.x + hr.x));
        m1 = fmaxf(m1, alpha * (hs.y + hr.y));
    }
    if (deg == 0) { m0 = 0.f; m1 = 0.f; }
    a[wv][2 * lane] = m0;       // 2-way bank aliasing = free on gfx950
    a[wv][2 * lane + 1] = m1;
    __syncthreads();
    // epilogue: out[g][c], out[g+4][c]; each wave reads one a-row pair
    // uniformly (LDS broadcast), W_h column reads coalesced across the wave.
    const int c = threadIdx.x & 127;
    const int g = threadIdx.x >> 7;  // 0..3
    float acc0 = 0.f, acc1 = 0.f;
#pragma unroll 4
    for (int kq = 0; kq < IN_DIM / 4; ++kq) {
        const float4 a0 = *(const float4*)(&a[g][4 * kq]);
        const float4 a1 = *(const float4*)(&a[g + 4][4 * kq]);
        const float w0 = W_h[(4 * kq + 0) * OUT_DIM + c];
        const float w1 = W_h[(4 * kq + 1) * OUT_DIM + c];
        const float w2 = W_h[(4 * kq + 2) * OUT_DIM + c];
        const float w3 = W_h[(4 * kq + 3) * OUT_DIM + c];
        acc0 = fmaf(a0.x, w0, fmaf(a0.y, w1, fmaf(a0.z, w2, fmaf(a0.w, w3, acc0))));
        acc1 = fmaf(a1.x, w0, fmaf(a1.y, w1, fmaf(a1.z, w2, fmaf(a1.w, w3, acc1))));
    }
    const long nb = (long)blockIdx.x * 8;
    out[(nb + g) * OUT_DIM + c] = acc0;
    out[(nb + g + 4) * OUT_DIM + c] = acc1;
}

extern "C" void kernel_launch(void* const* d_in, const int* in_sizes, int n_in,
                              void* d_out, int out_size, void* d_ws, size_t ws_size,
                              hipStream_t stream) {
    const int* q_rel = (const int*)d_in[1];
    const float* hidden = (const float*)d_in[2];
    const int* edges = (const int*)d_in[3];
    const float* rela = (const float*)d_in[7];
    const float* Ws = (const float*)d_in[8];
    const float* Wr = (const float*)d_in[9];
    const float* Wqr = (const float*)d_in[10];
    const float* bqr = (const float*)d_in[11];
    const float* wa = (const float*)d_in[12];
    const float* ba = (const float*)d_in[13];
    const float* W_h = (const float*)d_in[14];
    float* out = (float*)d_out;

    char* ws = (char*)d_ws;
    float* sW = (float*)(ws);                    // 25,600,000 B
    float* rW = (float*)(ws + 25600000);         //    102,656 B
    float* qW = (float*)(ws + 25702656);         //     16,384 B
    int* cnt = (int*)(ws + 25719040);            //    400,000 B
    int* incl = (int*)(ws + 26119040);           //    400,000 B
    int* offs = (int*)(ws + 26519040);           //    400,000 B
    int* cursor = (int*)(ws + 26919040);         //    400,000 B
    int* bsum = (int*)(ws + 27319040);           //      2,048 B
    unsigned* rec = (unsigned*)(ws + 27321088);  //  3,200,000 B  (total ~30.5 MB)

    hipLaunchKernelGGL(k_sw, dim3(N_NODE / 8), dim3(64), 0, stream, hidden, Ws, sW);
    hipLaunchKernelGGL(k_relq, dim3(N_RELA + BATCH), dim3(64), 0, stream,
                       rela, Wr, Wqr, bqr, q_rel, rW, qW);
    hipLaunchKernelGGL(k_zero, dim3(N_SCANB), dim3(256), 0, stream, cnt);
    hipLaunchKernelGGL(k_count, dim3(N_EDGE / 256), dim3(256), 0, stream, edges, cnt);
    hipLaunchKernelGGL(k_scan1, dim3(N_SCANB), dim3(SCAN_B), 0, stream, cnt, incl, bsum);
    hipLaunchKernelGGL(k_scan2, dim3(1), dim3(512), 0, stream, bsum);
    hipLaunchKernelGGL(k_scan3, dim3(N_SCANB), dim3(SCAN_B), 0, stream,
                       incl, cnt, bsum, offs, cursor);
    hipLaunchKernelGGL(k_scatter, dim3(N_EDGE / 256), dim3(256), 0, stream,
                       edges, cursor, rec);
    hipLaunchKernelGGL(k_fused, dim3(N_NODE / 8), dim3(512), 0, stream,
                       rec, offs, cnt, hidden, rela, sW, rW, qW, wa, ba, W_h, out);
}